// Round 1
// baseline (168.960 us; speedup 1.0000x reference)
//
#include <hip/hip_runtime.h>

// SensorAutoEncoder: 10-layer MLP over 1M rows of 43 floats, fused in one
// persistent kernel. fp16 MFMA (16x16x32) with fp32 accumulate; weights +
// per-wave h-buffers in LDS; bias folded into K-dimension; no barriers in
// the main loop (wave-private buffers).

typedef _Float16 f16x8 __attribute__((ext_vector_type(8)));
typedef float f32x4 __attribute__((ext_vector_type(4)));

#define TPB 512
#define NBLK 256
#define ITERS 16
#define NROWS 1048576
#define NCOL 43
#define WSTRIDE 72                       // halfwords per row (bank-balanced)
#define WSLOT (48 * WSTRIDE)             // 3456 halfwords per layer slot
#define W_BYTES (10 * WSLOT * 2)         // 69120 B
#define XBUF_BYTES 6144                  // 32 rows * 43 f32 = 5504, pad to 6 KiB
#define X_BASE W_BYTES
#define HBUF_BYTES (32 * WSTRIDE * 2)    // 4608 B
#define H_BASE (X_BASE + 8 * XBUF_BYTES) // 118272
#define SMEM_BYTES (H_BASE + 8 * HBUF_BYTES) // 155136 <= 160 KiB

__device__ __forceinline__ float fast_tanh(float x) {
  // tanh(x) = 1 - 2/(1 + e^{2x});  e^{2x} = 2^{x * 2*log2(e)}
  float t = __builtin_amdgcn_exp2f(x * 2.8853900817779268f);
  float r = __builtin_amdgcn_rcpf(t + 1.0f);
  return __builtin_fmaf(-2.0f, r, 1.0f);
}

__device__ __forceinline__ void gload_lds16(const void* g, void* l) {
  __builtin_amdgcn_global_load_lds(
      (const __attribute__((address_space(1))) void*)g,
      (__attribute__((address_space(3))) void*)l, 16, 0, 0);
}

// Issue async global->LDS DMA of one 32-row x tile (6 x 1KiB chunks).
// Per-lane global src (clamped so tail blocks never read OOB); uniform LDS base.
__device__ __forceinline__ void issue_dma(const float* x, const char* xlim,
                                          float* xb, size_t rowbase, int lane) {
  const char* base = (const char*)x + rowbase * (size_t)(NCOL * 4);
#pragma unroll
  for (int c = 0; c < 6; ++c) {
    const char* src = base + c * 1024 + lane * 16;
    src = (src > xlim) ? xlim : src;
    gload_lds16(src, (char*)xb + c * 1024);
  }
}

__device__ __forceinline__ void store_h4(_Float16* dst, float v0, float v1,
                                         float v2, float v3) {
  union { _Float16 h[4]; uint2 u; } p;
  p.h[0] = (_Float16)v0; p.h[1] = (_Float16)v1;
  p.h[2] = (_Float16)v2; p.h[3] = (_Float16)v3;
  *(uint2*)dst = p.u;   // 8B-aligned by construction -> ds_write_b64
}

// One hidden layer: read B-frags (h^T) from wave-private H, A-frags (W^T) from
// weight LDS, MFMA, epilogue (tanh + bias-column forcing), write H back.
// NT = output 16-col tiles, KC = 32-wide K chunks, NLOUT = real output width.
template <int NT, int KC, bool DOTANH, int NLOUT>
__device__ __forceinline__ void mid_layer(const _Float16* __restrict__ Wl,
                                          _Float16* Hw, int g, int lr) {
  f16x8 Bv[2][KC];
#pragma unroll
  for (int s = 0; s < 2; ++s)
#pragma unroll
    for (int c = 0; c < KC; ++c)
      Bv[s][c] = *(const f16x8*)(Hw + (16 * s + lr) * WSTRIDE + 8 * g + 32 * c);

  f32x4 acc[NT][2];
#pragma unroll
  for (int t = 0; t < NT; ++t)
#pragma unroll
    for (int s = 0; s < 2; ++s) acc[t][s] = f32x4{0.f, 0.f, 0.f, 0.f};

#pragma unroll
  for (int c = 0; c < KC; ++c)
#pragma unroll
    for (int t = 0; t < NT; ++t) {
      f16x8 A = *(const f16x8*)(Wl + (16 * t + lr) * WSTRIDE + 8 * g + 32 * c);
#pragma unroll
      for (int s = 0; s < 2; ++s)
        acc[t][s] = __builtin_amdgcn_mfma_f32_16x16x32_f16(A, Bv[s][c],
                                                           acc[t][s], 0, 0, 0);
    }

#pragma unroll
  for (int t = 0; t < NT; ++t)
#pragma unroll
    for (int s = 0; s < 2; ++s) {
      float v[4];
#pragma unroll
      for (int r = 0; r < 4; ++r) {
        int col = 16 * t + 4 * g + r;
        float u = acc[t][s][r];
        if (DOTANH) u = fast_tanh(u);
        // col == NLOUT -> 1.0 (bias row multiplier for next layer); beyond -> 0
        v[r] = (col < NLOUT) ? u : ((col == NLOUT) ? 1.0f : 0.0f);
      }
      store_h4(Hw + (16 * s + lr) * WSTRIDE + 16 * t + 4 * g,
               v[0], v[1], v[2], v[3]);
    }
}

extern "C" __global__ void __launch_bounds__(TPB, 2)
ae_kernel(const float* __restrict__ x,
          const float* __restrict__ W0, const float* __restrict__ B0,
          const float* __restrict__ W1, const float* __restrict__ B1,
          const float* __restrict__ W2, const float* __restrict__ B2,
          const float* __restrict__ W3, const float* __restrict__ B3,
          const float* __restrict__ W4, const float* __restrict__ B4,
          const float* __restrict__ W5, const float* __restrict__ B5,
          const float* __restrict__ W6, const float* __restrict__ B6,
          const float* __restrict__ W7, const float* __restrict__ B7,
          const float* __restrict__ W8, const float* __restrict__ B8,
          const float* __restrict__ W9, const float* __restrict__ B9,
          float* __restrict__ out) {
  extern __shared__ char smem[];
  _Float16* lw = (_Float16*)smem;

  const int tid = threadIdx.x;
  const int wave = tid >> 6;
  const int lane = tid & 63;
  const int g = lane >> 4;
  const int lr = lane & 15;

  // ---- stage all weights as fp16 W^T with bias row at k==K, zero padding ----
  {
    const float* Wp[10] = {W0, W1, W2, W3, W4, W5, W6, W7, W8, W9};
    const float* Bp[10] = {B0, B1, B2, B3, B4, B5, B6, B7, B8, B9};
    const int KLs[10] = {43, 43, 43, 43, 43, 21, 43, 43, 43, 43};
    const int NLs[10] = {43, 43, 43, 43, 21, 43, 43, 43, 43, 43};
#pragma unroll
    for (int L = 0; L < 10; ++L) {
      const float* Wl = Wp[L];
      const float* Bl = Bp[L];
      const int KL = KLs[L], NL = NLs[L];
      for (int idx = tid; idx < 48 * 64; idx += TPB) {
        int n = idx >> 6, k = idx & 63;
        float v = 0.0f;
        if (n < NL) {
          if (k < KL) v = Wl[k * NL + n];            // W^T[n][k] = W[k][n]
          else if (k == KL && L != 0) v = Bl[n];     // bias row (L0 explicit)
        }
        lw[L * WSLOT + n * WSTRIDE + k] = (_Float16)v;
      }
    }
  }

  float* xb = (float*)(smem + X_BASE + wave * XBUF_BYTES);
  _Float16* Hw = (_Float16*)(smem + H_BASE + wave * HBUF_BYTES);

  // zero wave-private H (pad cols 48..63 must stay 0: garbage fp16 * 0 = NaN)
  {
    unsigned* h32 = (unsigned*)Hw;
#pragma unroll
    for (int i = 0; i < 18; ++i) h32[lane + 64 * i] = 0;  // 1152 dwords
  }

  // layer-0 bias fragment (per-lane, matches C layout col = 16t+4g+r)
  float b0v[12];
#pragma unroll
  for (int t = 0; t < 3; ++t)
#pragma unroll
    for (int r = 0; r < 4; ++r) {
      int n = 16 * t + 4 * g + r;
      b0v[t * 4 + r] = (n < NCOL) ? B0[n] : 0.0f;
    }

  __syncthreads();  // weights ready; only barrier in the kernel

  const char* xlim = (const char*)x + (size_t)NROWS * NCOL * 4 - 16;
  const size_t blockrow = (size_t)blockIdx.x * (ITERS * 256);

  issue_dma(x, xlim, xb, blockrow + (size_t)(wave * 32), lane);

#pragma unroll 1
  for (int it = 0; it < ITERS; ++it) {
    const size_t row0 = blockrow + (size_t)it * 256 + (size_t)(wave * 32);
    asm volatile("s_waitcnt vmcnt(0)" ::: "memory");  // x tile landed in LDS

    // ---- layer 0: B-frags straight from staged fp32 x ----
    f16x8 Bv[2][2];
#pragma unroll
    for (int s = 0; s < 2; ++s)
#pragma unroll
      for (int c = 0; c < 2; ++c) {
        const float* xr = xb + (16 * s + lr) * NCOL + 8 * g + 32 * c;
        f16x8 v;
#pragma unroll
        for (int j = 0; j < 8; ++j) v[j] = (_Float16)xr[j];
        Bv[s][c] = v;
      }
    // x reads complete -> safe to start next tile's DMA into the same buffer
    asm volatile("s_waitcnt lgkmcnt(0)" ::: "memory");
    if (it < ITERS - 1)
      issue_dma(x, xlim, xb, row0 + 256, lane);

    f32x4 acc[3][2];
#pragma unroll
    for (int t = 0; t < 3; ++t)
#pragma unroll
      for (int s = 0; s < 2; ++s) acc[t][s] = f32x4{0.f, 0.f, 0.f, 0.f};
#pragma unroll
    for (int c = 0; c < 2; ++c)
#pragma unroll
      for (int t = 0; t < 3; ++t) {
        f16x8 A = *(const f16x8*)(lw + (16 * t + lr) * WSTRIDE + 8 * g + 32 * c);
#pragma unroll
        for (int s = 0; s < 2; ++s)
          acc[t][s] = __builtin_amdgcn_mfma_f32_16x16x32_f16(A, Bv[s][c],
                                                             acc[t][s], 0, 0, 0);
      }
#pragma unroll
    for (int t = 0; t < 3; ++t)
#pragma unroll
      for (int s = 0; s < 2; ++s) {
        float v[4];
#pragma unroll
        for (int r = 0; r < 4; ++r) {
          int col = 16 * t + 4 * g + r;
          float u = fast_tanh(acc[t][s][r] + b0v[t * 4 + r]);
          v[r] = (col < NCOL) ? u : ((col == NCOL) ? 1.0f : 0.0f);
        }
        store_h4(Hw + (16 * s + lr) * WSTRIDE + 16 * t + 4 * g,
                 v[0], v[1], v[2], v[3]);
      }

    // ---- layers 1..8 ----
    mid_layer<3, 2, true, 43>(lw + 1 * WSLOT, Hw, g, lr);
    mid_layer<3, 2, true, 43>(lw + 2 * WSLOT, Hw, g, lr);
    mid_layer<3, 2, true, 43>(lw + 3 * WSLOT, Hw, g, lr);
    mid_layer<2, 2, false, 21>(lw + 4 * WSLOT, Hw, g, lr);  // bottleneck, no tanh
    mid_layer<3, 1, true, 43>(lw + 5 * WSLOT, Hw, g, lr);   // K=21 -> 1 chunk
    mid_layer<3, 2, true, 43>(lw + 6 * WSLOT, Hw, g, lr);
    mid_layer<3, 2, true, 43>(lw + 7 * WSLOT, Hw, g, lr);
    mid_layer<3, 2, true, 43>(lw + 8 * WSLOT, Hw, g, lr);

    // ---- layer 9: linear, store fp32 to global ----
    {
      f16x8 B9[2][2];
#pragma unroll
      for (int s = 0; s < 2; ++s)
#pragma unroll
        for (int c = 0; c < 2; ++c)
          B9[s][c] = *(const f16x8*)(Hw + (16 * s + lr) * WSTRIDE + 8 * g + 32 * c);
      f32x4 a9[3][2];
#pragma unroll
      for (int t = 0; t < 3; ++t)
#pragma unroll
        for (int s = 0; s < 2; ++s) a9[t][s] = f32x4{0.f, 0.f, 0.f, 0.f};
#pragma unroll
      for (int c = 0; c < 2; ++c)
#pragma unroll
        for (int t = 0; t < 3; ++t) {
          f16x8 A = *(const f16x8*)(lw + 9 * WSLOT + (16 * t + lr) * WSTRIDE +
                                    8 * g + 32 * c);
#pragma unroll
          for (int s = 0; s < 2; ++s)
            a9[t][s] = __builtin_amdgcn_mfma_f32_16x16x32_f16(A, B9[s][c],
                                                              a9[t][s], 0, 0, 0);
        }
#pragma unroll
      for (int t = 0; t < 3; ++t)
#pragma unroll
        for (int s = 0; s < 2; ++s)
#pragma unroll
          for (int r = 0; r < 4; ++r) {
            int col = 16 * t + 4 * g + r;
            if (col < NCOL)
              out[(row0 + (size_t)(16 * s + lr)) * NCOL + col] = a9[t][s][r];
          }
    }
  }
}

extern "C" void kernel_launch(void* const* d_in, const int* in_sizes, int n_in,
                              void* d_out, int out_size, void* d_ws,
                              size_t ws_size, hipStream_t stream) {
  const float* x = (const float*)d_in[0];
  const float* W[10];
  const float* B[10];
  for (int i = 0; i < 10; ++i) {
    W[i] = (const float*)d_in[1 + 2 * i];
    B[i] = (const float*)d_in[2 + 2 * i];
  }
  hipFuncSetAttribute(reinterpret_cast<const void*>(ae_kernel),
                      hipFuncAttributeMaxDynamicSharedMemorySize, SMEM_BYTES);
  ae_kernel<<<dim3(NBLK), dim3(TPB), SMEM_BYTES, stream>>>(
      x, W[0], B[0], W[1], B[1], W[2], B[2], W[3], B[3], W[4], B[4],
      W[5], B[5], W[6], B[6], W[7], B[7], W[8], B[8], W[9], B[9],
      (float*)d_out);
}

// Round 3
// 159.859 us; speedup vs baseline: 1.0569x; 1.0569x over previous
//
#include <hip/hip_runtime.h>

// SensorAutoEncoder: 10-layer MLP over 1M rows of 43 floats, fused persistent
// kernel. fp16 MFMA (16x16x32) + fp32 accumulate. R3: same as R2 design
// (1024-thread blocks, x->registers prefetch, cvt_pkrtz packing) with the
// cvt_pkrtz return type fixed (__fp16 vector, not _Float16 vector).

typedef __fp16 pk16x2 __attribute__((ext_vector_type(2)));   // cvt_pkrtz type
typedef _Float16 f16x8 __attribute__((ext_vector_type(8)));
typedef float f32x4 __attribute__((ext_vector_type(4)));

#define TPB 1024
#define NBLK 256
#define ITERS 8
#define NROWS 1048576
#define NCOL 43
#define ROWB 172u                       // bytes per x row (43 f32)
#define XBYTES (NROWS * (size_t)ROWB)   // 180,355,072 (< 2^31, u32 offsets ok)
#define WSTRIDE 72                      // halfwords per row; 144 B rows
#define WSLOT (48 * WSTRIDE)            // 3456 halfwords per layer slot
#define W_BYTES (10 * WSLOT * 2)        // 69120 B
#define HBUF_HW (32 * WSTRIDE)          // 2304 halfwords per wave
#define HBUF_BYTES (HBUF_HW * 2)        // 4608 B
#define H_BASE W_BYTES
#define SMEM_BYTES (H_BASE + 16 * HBUF_BYTES)  // 142848 <= 160 KiB

__device__ __forceinline__ float fast_tanh(float x) {
  // tanh(x) = 1 - 2/(1 + e^{2x});  e^{2x} = 2^{x * 2*log2(e)}
  float t = __builtin_amdgcn_exp2f(x * 2.8853900817779268f);
  float r = __builtin_amdgcn_rcpf(t + 1.0f);
  return __builtin_fmaf(-2.0f, r, 1.0f);
}

__device__ __forceinline__ void store_h4(_Float16* dst, float v0, float v1,
                                         float v2, float v3) {
  union { pk16x2 h[2]; uint2 u; } p;
  p.h[0] = __builtin_amdgcn_cvt_pkrtz(v0, v1);
  p.h[1] = __builtin_amdgcn_cvt_pkrtz(v2, v3);
  *(uint2*)dst = p.u;   // 8B-aligned -> ds_write_b64
}

// One hidden layer: B-frags (h^T) from wave-private H, A-frags (W^T) from
// weight LDS, MFMA, epilogue (tanh + bias-column forcing), write H back.
template <int NT, int KC, bool DOTANH, int NLOUT>
__device__ __forceinline__ void mid_layer(const _Float16* __restrict__ Wl,
                                          _Float16* Hw, int g, int lr) {
  f16x8 Bv[2][KC];
#pragma unroll
  for (int s = 0; s < 2; ++s)
#pragma unroll
    for (int c = 0; c < KC; ++c)
      Bv[s][c] = *(const f16x8*)(Hw + (16 * s + lr) * WSTRIDE + 8 * g + 32 * c);

  f32x4 acc[NT][2];
#pragma unroll
  for (int t = 0; t < NT; ++t)
#pragma unroll
    for (int s = 0; s < 2; ++s) acc[t][s] = f32x4{0.f, 0.f, 0.f, 0.f};

#pragma unroll
  for (int c = 0; c < KC; ++c)
#pragma unroll
    for (int t = 0; t < NT; ++t) {
      f16x8 A = *(const f16x8*)(Wl + (16 * t + lr) * WSTRIDE + 8 * g + 32 * c);
#pragma unroll
      for (int s = 0; s < 2; ++s)
        acc[t][s] = __builtin_amdgcn_mfma_f32_16x16x32_f16(A, Bv[s][c],
                                                           acc[t][s], 0, 0, 0);
    }

#pragma unroll
  for (int t = 0; t < NT; ++t)
#pragma unroll
    for (int s = 0; s < 2; ++s) {
      float v[4];
#pragma unroll
      for (int r = 0; r < 4; ++r) {
        int col = 16 * t + 4 * g + r;
        float u = acc[t][s][r];
        if (DOTANH) u = fast_tanh(u);
        v[r] = (col < NLOUT) ? u : ((col == NLOUT) ? 1.0f : 0.0f);
      }
      store_h4(Hw + (16 * s + lr) * WSTRIDE + 16 * t + 4 * g,
               v[0], v[1], v[2], v[3]);
    }
}

extern "C" __global__ void __launch_bounds__(TPB, 1)
ae_kernel(const float* __restrict__ x,
          const float* __restrict__ W0, const float* __restrict__ B0,
          const float* __restrict__ W1, const float* __restrict__ B1,
          const float* __restrict__ W2, const float* __restrict__ B2,
          const float* __restrict__ W3, const float* __restrict__ B3,
          const float* __restrict__ W4, const float* __restrict__ B4,
          const float* __restrict__ W5, const float* __restrict__ B5,
          const float* __restrict__ W6, const float* __restrict__ B6,
          const float* __restrict__ W7, const float* __restrict__ B7,
          const float* __restrict__ W8, const float* __restrict__ B8,
          const float* __restrict__ W9, const float* __restrict__ B9,
          float* __restrict__ out) {
  extern __shared__ char smem[];
  _Float16* lw = (_Float16*)smem;

  const int tid = threadIdx.x;
  const int wave = tid >> 6;
  const int lane = tid & 63;
  const int g = lane >> 4;
  const int lr = lane & 15;

  // ---- stage all weights as fp16 W^T with bias row at k==K, zero padding ----
  {
    const float* Wp[10] = {W0, W1, W2, W3, W4, W5, W6, W7, W8, W9};
    const float* Bp[10] = {B0, B1, B2, B3, B4, B5, B6, B7, B8, B9};
    const int KLs[10] = {43, 43, 43, 43, 43, 21, 43, 43, 43, 43};
    const int NLs[10] = {43, 43, 43, 43, 21, 43, 43, 43, 43, 43};
#pragma unroll
    for (int L = 0; L < 10; ++L) {
      const float* Wl = Wp[L];
      const float* Bl = Bp[L];
      const int KL = KLs[L], NL = NLs[L];
      for (int idx = tid; idx < 48 * 64; idx += TPB) {
        int n = idx >> 6, k = idx & 63;
        float v = 0.0f;
        if (n < NL) {
          if (k < KL) v = Wl[k * NL + n];            // W^T[n][k] = W[k][n]
          else if (k == KL && L != 0) v = Bl[n];     // bias row (L0 explicit)
        }
        lw[L * WSLOT + n * WSTRIDE + k] = (_Float16)v;
      }
    }
  }

  _Float16* Hw = (_Float16*)(smem + H_BASE + wave * HBUF_BYTES);

  // zero wave-private H (pad cols 48..63 must stay 0)
  {
    unsigned* h32 = (unsigned*)Hw;
#pragma unroll
    for (int i = 0; i < 18; ++i) h32[lane + 64 * i] = 0;  // 1152 dwords
  }

  // layer-0 bias fragment (per-lane, matches C layout col = 16t+4g+r)
  float b0v[12];
#pragma unroll
  for (int t = 0; t < 3; ++t)
#pragma unroll
    for (int r = 0; r < 4; ++r) {
      int n = 16 * t + 4 * g + r;
      b0v[t * 4 + r] = (n < NCOL) ? B0[n] : 0.0f;
    }

  // per-lane masks for the c=1 K-chunk of layer 0 (k = 32+8g+j < 43)
  pk16x2 m1[4];
#pragma unroll
  for (int j2 = 0; j2 < 4; ++j2) {
    m1[j2][0] = (__fp16)((32 + 8 * g + 2 * j2 + 0 < NCOL) ? 1.0f : 0.0f);
    m1[j2][1] = (__fp16)((32 + 8 * g + 2 * j2 + 1 < NCOL) ? 1.0f : 0.0f);
  }

  __syncthreads();  // weights ready; only barrier in the kernel

  const char* xc = (const char*)x;
  const unsigned blockbase = (unsigned)blockIdx.x * (ITERS * 512) + wave * 32;
  const unsigned LIM = (unsigned)(XBYTES - 4);

  float xv0[2][8], xv1[2][8];
  // prefetch iteration 0
#pragma unroll
  for (int s = 0; s < 2; ++s) {
    unsigned rb = (blockbase + 16 * s + lr) * ROWB;
    unsigned a0 = rb + 32u * g;
    unsigned a1 = rb + 128u + 32u * g;
#pragma unroll
    for (int j = 0; j < 8; ++j) {
      xv0[s][j] = *(const float*)(xc + (a0 + 4u * j));
      unsigned a = a1 + 4u * j;
      xv1[s][j] = *(const float*)(xc + (a < LIM ? a : LIM));
    }
  }

#pragma unroll 1
  for (int it = 0; it < ITERS; ++it) {
    const unsigned row0 = blockbase + (unsigned)it * 512u;

    // ---- build layer-0 B-frags from prefetched registers ----
    f16x8 Bv[2][2];
#pragma unroll
    for (int s = 0; s < 2; ++s) {
      union { pk16x2 h[4]; f16x8 v; } u0, u1;
#pragma unroll
      for (int j2 = 0; j2 < 4; ++j2) {
        u0.h[j2] = __builtin_amdgcn_cvt_pkrtz(xv0[s][2 * j2], xv0[s][2 * j2 + 1]);
        u1.h[j2] = __builtin_amdgcn_cvt_pkrtz(xv1[s][2 * j2], xv1[s][2 * j2 + 1])
                   * m1[j2];
      }
      Bv[s][0] = u0.v;
      Bv[s][1] = u1.v;
    }

    // ---- prefetch next iteration's x into registers ----
    if (it + 1 < ITERS) {
#pragma unroll
      for (int s = 0; s < 2; ++s) {
        unsigned rb = (row0 + 512u + 16 * s + lr) * ROWB;
        unsigned a0 = rb + 32u * g;
        unsigned a1 = rb + 128u + 32u * g;
#pragma unroll
        for (int j = 0; j < 8; ++j) {
          xv0[s][j] = *(const float*)(xc + (a0 + 4u * j));
          unsigned a = a1 + 4u * j;
          xv1[s][j] = *(const float*)(xc + (a < LIM ? a : LIM));
        }
      }
    }

    // ---- layer 0 ----
    f32x4 acc[3][2];
#pragma unroll
    for (int t = 0; t < 3; ++t)
#pragma unroll
      for (int s = 0; s < 2; ++s) acc[t][s] = f32x4{0.f, 0.f, 0.f, 0.f};
#pragma unroll
    for (int c = 0; c < 2; ++c)
#pragma unroll
      for (int t = 0; t < 3; ++t) {
        f16x8 A = *(const f16x8*)(lw + (16 * t + lr) * WSTRIDE + 8 * g + 32 * c);
#pragma unroll
        for (int s = 0; s < 2; ++s)
          acc[t][s] = __builtin_amdgcn_mfma_f32_16x16x32_f16(A, Bv[s][c],
                                                             acc[t][s], 0, 0, 0);
      }
#pragma unroll
    for (int t = 0; t < 3; ++t)
#pragma unroll
      for (int s = 0; s < 2; ++s) {
        float v[4];
#pragma unroll
        for (int r = 0; r < 4; ++r) {
          int col = 16 * t + 4 * g + r;
          float u = fast_tanh(acc[t][s][r] + b0v[t * 4 + r]);
          v[r] = (col < NCOL) ? u : ((col == NCOL) ? 1.0f : 0.0f);
        }
        store_h4(Hw + (16 * s + lr) * WSTRIDE + 16 * t + 4 * g,
                 v[0], v[1], v[2], v[3]);
      }

    // ---- layers 1..8 ----
    mid_layer<3, 2, true, 43>(lw + 1 * WSLOT, Hw, g, lr);
    mid_layer<3, 2, true, 43>(lw + 2 * WSLOT, Hw, g, lr);
    mid_layer<3, 2, true, 43>(lw + 3 * WSLOT, Hw, g, lr);
    mid_layer<2, 2, false, 21>(lw + 4 * WSLOT, Hw, g, lr);  // bottleneck
    mid_layer<3, 1, true, 43>(lw + 5 * WSLOT, Hw, g, lr);   // K=21 -> 1 chunk
    mid_layer<3, 2, true, 43>(lw + 6 * WSLOT, Hw, g, lr);
    mid_layer<3, 2, true, 43>(lw + 7 * WSLOT, Hw, g, lr);
    mid_layer<3, 2, true, 43>(lw + 8 * WSLOT, Hw, g, lr);

    // ---- layer 9: linear, store fp32 to global ----
    {
      f16x8 B9[2][2];
#pragma unroll
      for (int s = 0; s < 2; ++s)
#pragma unroll
        for (int c = 0; c < 2; ++c)
          B9[s][c] = *(const f16x8*)(Hw + (16 * s + lr) * WSTRIDE + 8 * g + 32 * c);
      f32x4 a9[3][2];
#pragma unroll
      for (int t = 0; t < 3; ++t)
#pragma unroll
        for (int s = 0; s < 2; ++s) a9[t][s] = f32x4{0.f, 0.f, 0.f, 0.f};
#pragma unroll
      for (int c = 0; c < 2; ++c)
#pragma unroll
        for (int t = 0; t < 3; ++t) {
          f16x8 A = *(const f16x8*)(lw + 9 * WSLOT + (16 * t + lr) * WSTRIDE +
                                    8 * g + 32 * c);
#pragma unroll
          for (int s = 0; s < 2; ++s)
            a9[t][s] = __builtin_amdgcn_mfma_f32_16x16x32_f16(A, B9[s][c],
                                                              a9[t][s], 0, 0, 0);
        }
#pragma unroll
      for (int t = 0; t < 3; ++t)
#pragma unroll
        for (int s = 0; s < 2; ++s)
#pragma unroll
          for (int r = 0; r < 4; ++r) {
            int col = 16 * t + 4 * g + r;
            if (col < NCOL)
              out[(size_t)(row0 + 16 * s + lr) * NCOL + col] = a9[t][s][r];
          }
    }
  }
}

extern "C" void kernel_launch(void* const* d_in, const int* in_sizes, int n_in,
                              void* d_out, int out_size, void* d_ws,
                              size_t ws_size, hipStream_t stream) {
  const float* x = (const float*)d_in[0];
  const float* W[10];
  const float* B[10];
  for (int i = 0; i < 10; ++i) {
    W[i] = (const float*)d_in[1 + 2 * i];
    B[i] = (const float*)d_in[2 + 2 * i];
  }
  (void)hipFuncSetAttribute(reinterpret_cast<const void*>(ae_kernel),
                            hipFuncAttributeMaxDynamicSharedMemorySize,
                            SMEM_BYTES);
  ae_kernel<<<dim3(NBLK), dim3(TPB), SMEM_BYTES, stream>>>(
      x, W[0], B[0], W[1], B[1], W[2], B[2], W[3], B[3], W[4], B[4],
      W[5], B[5], W[6], B[6], W[7], B[7], W[8], B[8], W[9], B[9],
      (float*)d_out);
}